// Round 1
// baseline (395.403 us; speedup 1.0000x reference)
//
#include <hip/hip_runtime.h>

#define N 8192
#define DIM 128
#define NCHUNK 32   // j-chunks in pass 1 -> partial[NCHUNK][N]

// ---------------------------------------------------------------------------
// Pass 0: encoder MLP. 128 -> 64 -> 32 -> 16 -> 16, relu on first three.
// One thread per row, 64-thread blocks (1 wave), weights staged in LDS.
// Hidden activations round-trip through per-thread LDS columns (padded
// strides so lane t + uniform j hits distinct banks) to allow dynamic
// indexing without register spills.
// ---------------------------------------------------------------------------
__global__ __launch_bounds__(64) void encoder_kernel(
    const float* __restrict__ x,
    const float* __restrict__ W1, const float* __restrict__ b1,
    const float* __restrict__ W2, const float* __restrict__ b2,
    const float* __restrict__ W3, const float* __restrict__ b3,
    const float* __restrict__ W4, const float* __restrict__ b4,
    float* __restrict__ z, float* __restrict__ sqout)
{
    __shared__ float sW2[64 * 32];
    __shared__ float sW3[32 * 16];
    __shared__ float sW4[16 * 16];
    __shared__ float sb1[64];
    __shared__ float sb2[32];
    __shared__ float sb3[16];
    __shared__ float sb4[16];
    __shared__ float sW1[128 * 64];   // reused for h2/h3 staging after layer 1
    __shared__ float sh1[64 * 65];    // stride 65: bank = (t + k) % 32, conflict-free

    int t = threadIdx.x;
    float* sh2 = sW1;                 // 64*33 = 2112 floats
    float* sh3 = sW1 + 2112;          // 64*17 = 1088 floats  (3200 <= 8192, fits)

    for (int idx = t; idx < 128 * 64; idx += 64) sW1[idx] = W1[idx];
    for (int idx = t; idx < 64 * 32; idx += 64) sW2[idx] = W2[idx];
    for (int idx = t; idx < 32 * 16; idx += 64) sW3[idx] = W3[idx];
    for (int idx = t; idx < 16 * 16; idx += 64) sW4[idx] = W4[idx];
    sb1[t] = b1[t];
    if (t < 32) sb2[t] = b2[t];
    if (t < 16) { sb3[t] = b3[t]; sb4[t] = b4[t]; }
    __syncthreads();

    int row = blockIdx.x * 64 + t;
    const float4* xr = (const float4*)(x + (size_t)row * DIM);

    // ---- layer 1: 128 -> 64 ----
    float h1[64];
    #pragma unroll
    for (int k = 0; k < 64; ++k) h1[k] = sb1[k];
    for (int j4 = 0; j4 < 32; ++j4) {
        float4 xv = xr[j4];
        const float* w0 = &sW1[(j4 * 4 + 0) * 64];
        const float* w1 = &sW1[(j4 * 4 + 1) * 64];
        const float* w2 = &sW1[(j4 * 4 + 2) * 64];
        const float* w3 = &sW1[(j4 * 4 + 3) * 64];
        #pragma unroll
        for (int k = 0; k < 64; ++k) h1[k] = fmaf(xv.x, w0[k], h1[k]);
        #pragma unroll
        for (int k = 0; k < 64; ++k) h1[k] = fmaf(xv.y, w1[k], h1[k]);
        #pragma unroll
        for (int k = 0; k < 64; ++k) h1[k] = fmaf(xv.z, w2[k], h1[k]);
        #pragma unroll
        for (int k = 0; k < 64; ++k) h1[k] = fmaf(xv.w, w3[k], h1[k]);
    }
    #pragma unroll
    for (int k = 0; k < 64; ++k) sh1[t * 65 + k] = fmaxf(h1[k], 0.0f);

    // ---- layer 2: 64 -> 32 ----  (single-wave block: in-order LDS ops make
    // the sW1 -> sh2 reuse safe; layer-1 reads complete before these writes)
    float h2[32];
    #pragma unroll
    for (int k = 0; k < 32; ++k) h2[k] = sb2[k];
    for (int j = 0; j < 64; ++j) {
        float a = sh1[t * 65 + j];
        #pragma unroll
        for (int k = 0; k < 32; ++k) h2[k] = fmaf(a, sW2[j * 32 + k], h2[k]);
    }
    #pragma unroll
    for (int k = 0; k < 32; ++k) sh2[t * 33 + k] = fmaxf(h2[k], 0.0f);

    // ---- layer 3: 32 -> 16 ----
    float h3[16];
    #pragma unroll
    for (int k = 0; k < 16; ++k) h3[k] = sb3[k];
    for (int j = 0; j < 32; ++j) {
        float a = sh2[t * 33 + j];
        #pragma unroll
        for (int k = 0; k < 16; ++k) h3[k] = fmaf(a, sW3[j * 16 + k], h3[k]);
    }
    #pragma unroll
    for (int k = 0; k < 16; ++k) sh3[t * 17 + k] = fmaxf(h3[k], 0.0f);

    // ---- layer 4: 16 -> 16, no relu ----
    float zo[16];
    #pragma unroll
    for (int k = 0; k < 16; ++k) zo[k] = sb4[k];
    for (int j = 0; j < 16; ++j) {
        float a = sh3[t * 17 + j];
        #pragma unroll
        for (int k = 0; k < 16; ++k) zo[k] = fmaf(a, sW4[j * 16 + k], zo[k]);
    }

    float s = 0.0f;
    #pragma unroll
    for (int k = 0; k < 16; ++k) s = fmaf(zo[k], zo[k], s);
    sqout[row] = s;
    float4* zr = (float4*)(z + (size_t)row * 16);
    zr[0] = make_float4(zo[0], zo[1], zo[2], zo[3]);
    zr[1] = make_float4(zo[4], zo[5], zo[6], zo[7]);
    zr[2] = make_float4(zo[8], zo[9], zo[10], zo[11]);
    zr[3] = make_float4(zo[12], zo[13], zo[14], zo[15]);
}

// ---------------------------------------------------------------------------
// Pass 1: row sums of numerator = 1/(1+dist). Grid (16 rowblocks, 32 jchunks).
// Each thread owns rows i0 and i0+4096 (2 independent dot chains for ILP),
// one 256-wide j tile per block staged in LDS (all-lane broadcast reads).
// ---------------------------------------------------------------------------
__global__ __launch_bounds__(256) void pass1_kernel(
    const float* __restrict__ z, const float* __restrict__ sq,
    float* __restrict__ partial)
{
    __shared__ float s_zj[256 * 16];
    __shared__ float s_sqj[256];

    int t = threadIdx.x;
    int i0 = blockIdx.x * 256 + t;      // 0..4095
    int i1 = i0 + 4096;
    int jb = blockIdx.y * 256;

    // stage z tile for this block's j range
    {
        const float4* src = (const float4*)(z + (size_t)(jb + t) * 16);
        float4* dst = (float4*)(s_zj + t * 16);
        dst[0] = src[0]; dst[1] = src[1]; dst[2] = src[2]; dst[3] = src[3];
        s_sqj[t] = sq[jb + t];
    }

    float zi0[16], zi1[16];
    {
        const float4* p0 = (const float4*)(z + (size_t)i0 * 16);
        const float4* p1 = (const float4*)(z + (size_t)i1 * 16);
        #pragma unroll
        for (int q = 0; q < 4; ++q) {
            float4 v0 = p0[q]; float4 v1 = p1[q];
            zi0[4*q] = v0.x; zi0[4*q+1] = v0.y; zi0[4*q+2] = v0.z; zi0[4*q+3] = v0.w;
            zi1[4*q] = v1.x; zi1[4*q+1] = v1.y; zi1[4*q+2] = v1.z; zi1[4*q+3] = v1.w;
        }
    }
    float sqi0 = sq[i0], sqi1 = sq[i1];
    __syncthreads();

    float acc0 = 0.0f, acc1 = 0.0f;
    #pragma unroll 4
    for (int jj = 0; jj < 256; ++jj) {
        const float* zj = s_zj + jj * 16;
        float d0 = 0.0f, d1 = 0.0f;
        #pragma unroll
        for (int k = 0; k < 16; ++k) {
            float w = zj[k];
            d0 = fmaf(zi0[k], w, d0);
            d1 = fmaf(zi1[k], w, d1);
        }
        float sj = s_sqj[jj];
        float dist0 = fmaxf(fmaf(-2.0f, d0, sqi0 + sj), 0.0f);
        float dist1 = fmaxf(fmaf(-2.0f, d1, sqi1 + sj), 0.0f);
        acc0 += __builtin_amdgcn_rcpf(1.0f + dist0);
        acc1 += __builtin_amdgcn_rcpf(1.0f + dist1);
    }
    partial[blockIdx.y * N + i0] = acc0;
    partial[blockIdx.y * N + i1] = acc1;
}

// ---------------------------------------------------------------------------
// Pass 2: recompute numerators, scale by 1/rowsum, stream to out.
// Block = 16 i-rows (in LDS, broadcast reads) x 256 j per tile (thread-owned,
// coalesced nontemporal stores). 512 blocks -> 2 blocks/CU.
// ---------------------------------------------------------------------------
__global__ __launch_bounds__(256) void pass2_kernel(
    const float* __restrict__ z, const float* __restrict__ sq,
    const float* __restrict__ partial, float* __restrict__ out)
{
    __shared__ float s_zi[16 * 16];
    __shared__ float s_sqi[16];
    __shared__ float s_inv[16];
    __shared__ float s_red[16 * NCHUNK];

    int t = threadIdx.x;
    int ibase = blockIdx.x * 16;

    s_zi[t] = z[(size_t)ibase * 16 + t];
    if (t < 16) s_sqi[t] = sq[ibase + t];
    for (int q = t; q < 16 * NCHUNK; q += 256) {
        int ii = q >> 5;          // /NCHUNK
        int c  = q & (NCHUNK - 1);
        s_red[ii * NCHUNK + c] = partial[(size_t)c * N + ibase + ii];
    }
    __syncthreads();
    if (t < 16) {
        float s = 0.0f;
        #pragma unroll
        for (int c = 0; c < NCHUNK; ++c) s += s_red[t * NCHUNK + c];
        s_inv[t] = 1.0f / s;
    }
    __syncthreads();

    for (int jb = 0; jb < N; jb += 256) {
        int j = jb + t;
        float zj[16];
        {
            const float4* zp = (const float4*)(z + (size_t)j * 16);
            #pragma unroll
            for (int q = 0; q < 4; ++q) {
                float4 v = zp[q];
                zj[4*q] = v.x; zj[4*q+1] = v.y; zj[4*q+2] = v.z; zj[4*q+3] = v.w;
            }
        }
        float sqj = sq[j];
        #pragma unroll
        for (int ii = 0; ii < 16; ++ii) {
            const float* zi = s_zi + ii * 16;
            float d = 0.0f;
            #pragma unroll
            for (int k = 0; k < 16; ++k) d = fmaf(zi[k], zj[k], d);
            float dist = fmaxf(fmaf(-2.0f, d, s_sqi[ii] + sqj), 0.0f);
            float num = __builtin_amdgcn_rcpf(1.0f + dist);
            __builtin_nontemporal_store(num * s_inv[ii],
                                        &out[(size_t)(ibase + ii) * N + j]);
        }
    }
}

extern "C" void kernel_launch(void* const* d_in, const int* in_sizes, int n_in,
                              void* d_out, int out_size, void* d_ws, size_t ws_size,
                              hipStream_t stream) {
    const float* x  = (const float*)d_in[0];
    const float* W1 = (const float*)d_in[1];
    const float* b1 = (const float*)d_in[2];
    const float* W2 = (const float*)d_in[3];
    const float* b2 = (const float*)d_in[4];
    const float* W3 = (const float*)d_in[5];
    const float* b3 = (const float*)d_in[6];
    const float* W4 = (const float*)d_in[7];
    const float* b4 = (const float*)d_in[8];
    float* out = (float*)d_out;

    float* ws = (float*)d_ws;
    float* z       = ws;                    // N*16        = 131072 floats
    float* sq      = ws + N * 16;           // N           =   8192 floats
    float* partial = ws + N * 16 + N;       // NCHUNK*N    = 262144 floats
    // total ws usage: 401408 floats = 1.53 MiB

    encoder_kernel<<<128, 64, 0, stream>>>(x, W1, b1, W2, b2, W3, b3, W4, b4, z, sq);
    pass1_kernel<<<dim3(16, NCHUNK), 256, 0, stream>>>(z, sq, partial);
    pass2_kernel<<<N / 16, 256, 0, stream>>>(z, sq, partial, out);
}